// Round 2
// baseline (218.772 us; speedup 1.0000x reference)
//
#include <hip/hip_runtime.h>

#define R_    116
#define RP    128
#define DIN_  116
#define H_    256

typedef float  f32x4  __attribute__((ext_vector_type(4)));
typedef float  f32x2  __attribute__((ext_vector_type(2)));
typedef short  short8 __attribute__((ext_vector_type(8)));
typedef int    int4v  __attribute__((ext_vector_type(4)));

// ---- LDS layout (bytes) ----
#define AT_P     136      // At pitch (elements); 272B rows -> 16B aligned, 2-way bank alias (free)
#define H1_P     264      // H1 pitch; 528B rows -> 16B aligned
#define AT_OFF   0        // At [128][136] bf16 : At[c][r] = max(m[r][c],0) + (r==c)
#define H1_OFF   34816    // H1 [128][264] bf16 : h1[c][f]
#define DINV_OFF 102400   // 128 f32
#define RED_OFF  102912   // 16 f32
#define LDS_SIZE 102976

__device__ __forceinline__ short f2bf(float f) {
  union { float f; unsigned u; } x; x.f = f;
  unsigned r = x.u + 0x7fffu + ((x.u >> 16) & 1u);
  return (short)(r >> 16);
}
__device__ __forceinline__ float bf2f(short s) {
  union { unsigned u; float f; } x;
  x.u = ((unsigned)(unsigned short)s) << 16;
  return x.f;
}
__device__ __forceinline__ unsigned pack2(float lo, float hi) {
  return (unsigned)(unsigned short)f2bf(lo) | ((unsigned)(unsigned short)f2bf(hi) << 16);
}

union U8 { short8 s; unsigned u[4]; };

// Pre-transpose weights to bf16 Wt[f][k] with zero-padded K (layer 1).
__global__ void __launch_bounds__(256) wt_setup(const float* __restrict__ W1,
                                                const float* __restrict__ W2,
                                                short* __restrict__ W1t,
                                                short* __restrict__ W2t) {
  int idx = blockIdx.x * 256 + threadIdx.x;      // 384 blocks -> 98304 threads
  if (idx < 32768) {                             // W1t [256][128]
    int f = idx >> 7, k = idx & 127;
    float v = (k < DIN_) ? W1[k * H_ + f] : 0.f;
    W1t[idx] = f2bf(v);
  } else {                                       // W2t [256][256]
    int j = idx - 32768;
    int f = j >> 8, k = j & 255;
    W2t[j] = f2bf(W2[k * H_ + f]);
  }
}

// In-register xs -> agg. acc holds xw (C/D layout: f=ln16 col, r=q*4+e rows per tile).
// Produces acc2 += At @ (dinv*xw) over k=0..127 via intra-wave shuffle B-frags.
__device__ __forceinline__ void agg_from_acc(const f32x4* acc, const f32x4* dvr,
                                             char* smem, int i16, int q,
                                             f32x4* acc2) {
  unsigned P[8][2];
#pragma unroll
  for (int mt = 0; mt < 8; ++mt) {
#pragma unroll
    for (int j = 0; j < 2; ++j)
      P[mt][j] = pack2(acc[mt][2 * j] * dvr[mt][2 * j],
                       acc[mt][2 * j + 1] * dvr[mt][2 * j + 1]);
  }
  const int srcA = i16 + 32 * (q & 1);   // source lane for elements e=0..3
  const int srcB = srcA + 16;            // source lane for elements e=4..7
  const bool hi = q >= 2;                // which source tile (2ks vs 2ks+1)
#pragma unroll
  for (int ks = 0; ks < 4; ++ks) {
    unsigned a0 = (unsigned)__shfl((int)P[2 * ks][0], srcA);
    unsigned b0 = (unsigned)__shfl((int)P[2 * ks + 1][0], srcA);
    unsigned a1 = (unsigned)__shfl((int)P[2 * ks][1], srcA);
    unsigned b1 = (unsigned)__shfl((int)P[2 * ks + 1][1], srcA);
    unsigned a2 = (unsigned)__shfl((int)P[2 * ks][0], srcB);
    unsigned b2 = (unsigned)__shfl((int)P[2 * ks + 1][0], srcB);
    unsigned a3 = (unsigned)__shfl((int)P[2 * ks][1], srcB);
    unsigned b3 = (unsigned)__shfl((int)P[2 * ks + 1][1], srcB);
    U8 bf;
    bf.u[0] = hi ? b0 : a0;
    bf.u[1] = hi ? b1 : a1;
    bf.u[2] = hi ? b2 : a2;
    bf.u[3] = hi ? b3 : a3;
#pragma unroll
    for (int ct = 0; ct < 8; ++ct) {
      short8 atf = *(const short8*)(smem + AT_OFF +
                                    ((ct * 16 + i16) * AT_P + ks * 32 + q * 8) * 2);
      acc2[ct] = __builtin_amdgcn_mfma_f32_16x16x32_bf16(atf, bf.s, acc2[ct], 0, 0, 0);
    }
  }
}

__global__ void __launch_bounds__(512, 2) gnn_fused(
    const float* __restrict__ mM, const float* __restrict__ nf,
    const float* __restrict__ b1, const float* __restrict__ b2,
    const float* __restrict__ Wc, const float* __restrict__ bc,
    const short* __restrict__ W1t, const short* __restrict__ W2t,
    float* __restrict__ out)
{
  extern __shared__ char smem[];
  const int b    = blockIdx.x;
  const int tid  = threadIdx.x;
  const int lane = tid & 63;
  const int w    = tid >> 6;     // 0..7 : which 16-col f group
  const int i16  = lane & 15;
  const int q    = lane >> 4;

  float* dinvp = (float*)(smem + DINV_OFF);

  // ---- zero At (incl. padding rows/cols) ----
  for (int t = tid; t < (RP * AT_P * 2) / 16; t += 512)
    ((int4v*)(smem + AT_OFF))[t] = (int4v){0, 0, 0, 0};
  __syncthreads();

  // ---- fill At transposed, relu, +1 diag (float4 global reads) ----
  {
    const float* mB = mM + (size_t)b * (R_ * R_);   // 13456 = 4*3364, 16B aligned
    for (int t4 = tid; t4 < (R_ * R_) / 4; t4 += 512) {
      f32x4 v4 = ((const f32x4*)mB)[t4];
#pragma unroll
      for (int e = 0; e < 4; ++e) {
        int i = t4 * 4 + e;
        int r = i / R_, c = i - r * R_;
        float v = v4[e];
        v = v > 0.f ? v : 0.f;
        if (r == c) v += 1.f;
        *(short*)(smem + AT_OFF + (c * AT_P + r) * 2) = f2bf(v);
      }
    }
  }
  __syncthreads();

  // ---- deg/dinv: 4 threads per row, vector reads + shfl combine ----
  {
    int row = tid >> 2, part = tid & 3;
    float s = 0.f;
    const short8* rp = (const short8*)(smem + AT_OFF + (row * AT_P + part * 32) * 2);
#pragma unroll
    for (int j = 0; j < 4; ++j) {
      short8 v = rp[j];
#pragma unroll
      for (int e = 0; e < 8; ++e) s += bf2f(v[e]);
    }
    s += __shfl_xor(s, 1);
    s += __shfl_xor(s, 2);
    if ((tid & 3) == 0) dinvp[row] = (row < R_) ? rsqrtf(s) : 0.f;
  }
  __syncthreads();

  // dinv fragments (also reused as dinv[c] in epilogues; rows r>=116 -> 0)
  f32x4 dvr[8];
#pragma unroll
  for (int mt = 0; mt < 8; ++mt) dvr[mt] = *(const f32x4*)(dinvp + mt * 16 + q * 4);

  const int fbl = w * 16 + i16;

  // ================= Layer 1 =================
#pragma unroll 1
  for (int pass = 0; pass < 2; ++pass) {
    const int f = pass * 128 + fbl;
    f32x4 acc[8];
#pragma unroll
    for (int mt = 0; mt < 8; ++mt) acc[mt] = (f32x4){0.f, 0.f, 0.f, 0.f};

#pragma unroll
    for (int ks = 0; ks < 4; ++ks) {
      short8 wf = *(const short8*)(W1t + (size_t)f * 128 + ks * 32 + q * 8);
      const int k0 = ks * 32 + q * 8;
#pragma unroll
      for (int mt = 0; mt < 8; ++mt) {
        int r = mt * 16 + i16;
        int rc = r < R_ ? r : (R_ - 1);           // clamp; killed later by dinv=0
        const float* rowp = nf + (size_t)(b * R_ + rc) * DIN_;
        short8 af;
        if (k0 + 8 <= DIN_) {
          const f32x2* pp = (const f32x2*)(rowp + k0);  // rows are 8B aligned
          f32x2 p0 = pp[0], p1 = pp[1], p2 = pp[2], p3 = pp[3];
          af[0] = f2bf(p0[0]); af[1] = f2bf(p0[1]);
          af[2] = f2bf(p1[0]); af[3] = f2bf(p1[1]);
          af[4] = f2bf(p2[0]); af[5] = f2bf(p2[1]);
          af[6] = f2bf(p3[0]); af[7] = f2bf(p3[1]);
        } else {
#pragma unroll
          for (int e = 0; e < 8; ++e) {
            int k = k0 + e;
            float t = (k < DIN_) ? rowp[k] : 0.f;
            af[e] = f2bf(t);
          }
        }
        acc[mt] = __builtin_amdgcn_mfma_f32_16x16x32_bf16(af, wf, acc[mt], 0, 0, 0);
      }
    }

    f32x4 acc2[8];
#pragma unroll
    for (int ct = 0; ct < 8; ++ct) acc2[ct] = (f32x4){0.f, 0.f, 0.f, 0.f};
    agg_from_acc(acc, dvr, smem, i16, q, acc2);

    float bias = b1[f];
#pragma unroll
    for (int ct = 0; ct < 8; ++ct) {
#pragma unroll
      for (int e = 0; e < 4; ++e) {
        int c = ct * 16 + q * 4 + e;
        float h = dvr[ct][e] * acc2[ct][e] + bias;
        h = h > 0.f ? h : 0.2f * h;
        *(short*)(smem + H1_OFF + (c * H1_P + f) * 2) = f2bf(h);
      }
    }
  }
  __syncthreads();   // H1 complete

  // ================= Layer 2 =================
  float ps0 = 0.f, ps1 = 0.f;
#pragma unroll 1
  for (int pass = 0; pass < 2; ++pass) {
    const int f = pass * 128 + fbl;
    f32x4 acc[8];
#pragma unroll
    for (int mt = 0; mt < 8; ++mt) acc[mt] = (f32x4){0.f, 0.f, 0.f, 0.f};

#pragma unroll
    for (int ks = 0; ks < 8; ++ks) {
      short8 wf = *(const short8*)(W2t + (size_t)f * 256 + ks * 32 + q * 8);
#pragma unroll
      for (int mt = 0; mt < 8; ++mt) {
        short8 af = *(const short8*)(smem + H1_OFF +
                                     ((mt * 16 + i16) * H1_P + ks * 32 + q * 8) * 2);
        acc[mt] = __builtin_amdgcn_mfma_f32_16x16x32_bf16(af, wf, acc[mt], 0, 0, 0);
      }
    }

    f32x4 acc2[8];
#pragma unroll
    for (int ct = 0; ct < 8; ++ct) acc2[ct] = (f32x4){0.f, 0.f, 0.f, 0.f};
    agg_from_acc(acc, dvr, smem, i16, q, acc2);

    float bias = b2[f];
#pragma unroll
    for (int ct = 0; ct < 8; ++ct) {
#pragma unroll
      for (int e = 0; e < 4; ++e) {
        int c = ct * 16 + q * 4 + e;
        if (c < R_) {
          float h = dvr[ct][e] * acc2[ct][e] + bias;
          h = h > 0.f ? h : 0.2f * h;
          size_t j = (size_t)c * H_ + f;
          ps0 += h * Wc[j];
          ps1 += h * Wc[(size_t)(H_ * R_) + j];
        }
      }
    }
  }

  // ---- classifier reduction ----
#pragma unroll
  for (int off = 32; off; off >>= 1) {
    ps0 += __shfl_xor(ps0, off, 64);
    ps1 += __shfl_xor(ps1, off, 64);
  }
  float* red = (float*)(smem + RED_OFF);
  if (lane == 0) { red[w * 2] = ps0; red[w * 2 + 1] = ps1; }
  __syncthreads();
  if (tid == 0) {
    float s0 = 0.f, s1 = 0.f;
    for (int i = 0; i < 8; ++i) { s0 += red[i * 2]; s1 += red[i * 2 + 1]; }
    out[b * 2 + 0] = s0 + bc[0];
    out[b * 2 + 1] = s1 + bc[1];
  }
}

extern "C" void kernel_launch(void* const* d_in, const int* in_sizes, int n_in,
                              void* d_out, int out_size, void* d_ws, size_t ws_size,
                              hipStream_t stream) {
  const float* mM = (const float*)d_in[0];
  const float* nf = (const float*)d_in[1];
  const float* W1 = (const float*)d_in[2];
  const float* b1 = (const float*)d_in[3];
  const float* W2 = (const float*)d_in[4];
  const float* b2 = (const float*)d_in[5];
  const float* Wc = (const float*)d_in[6];
  const float* bc = (const float*)d_in[7];
  float* out = (float*)d_out;

  short* W1t = (short*)d_ws;            // 32768 bf16
  short* W2t = W1t + 32768;             // 65536 bf16

  wt_setup<<<384, 256, 0, stream>>>(W1, W2, W1t, W2t);

  hipFuncSetAttribute((const void*)gnn_fused,
                      hipFuncAttributeMaxDynamicSharedMemorySize, LDS_SIZE);
  gnn_fused<<<512, 512, LDS_SIZE, stream>>>(mM, nf, b1, b2, Wc, bc, W1t, W2t, out);
}

// Round 3
// 192.321 us; speedup vs baseline: 1.1375x; 1.1375x over previous
//
#include <hip/hip_runtime.h>

#define R_    116
#define RP    128
#define DIN_  116
#define H_    256

typedef float  f32x4  __attribute__((ext_vector_type(4)));
typedef short  short8 __attribute__((ext_vector_type(8)));
typedef int    int4v  __attribute__((ext_vector_type(4)));

// ---- LDS layout (bytes). All matrices XOR-swizzled: 16B-block index ^= (row&7).
#define AT_OFF   0        // At [128 c][128 r] bf16, pitch 256B : At[c][r]=max(m[r][c],0)+(r==c)
#define X_OFF    32768    // X  [128 r][128 k] bf16, pitch 256B : node features, zero-padded
#define H1_OFF   65536    // H1 [128 c][256 f] bf16, pitch 512B
#define DINV_OFF 131072   // 128 f32
#define RED_OFF  131584   // 16 f32
#define LDS_SIZE 131648

__device__ __forceinline__ short f2bf(float f) {
  union { float f; unsigned u; } x; x.f = f;
  unsigned r = x.u + 0x7fffu + ((x.u >> 16) & 1u);
  return (short)(r >> 16);
}
__device__ __forceinline__ float bf2f(short s) {
  union { unsigned u; float f; } x;
  x.u = ((unsigned)(unsigned short)s) << 16;
  return x.f;
}
__device__ __forceinline__ unsigned pack2(float lo, float hi) {
  return (unsigned)(unsigned short)f2bf(lo) | ((unsigned)(unsigned short)f2bf(hi) << 16);
}

union U8 { short8 s; unsigned u[4]; };

// Pre-transpose weights to bf16 Wt[f][k], zero-padded K (layer 1).
__global__ void __launch_bounds__(256) wt_setup(const float* __restrict__ W1,
                                                const float* __restrict__ W2,
                                                short* __restrict__ W1t,
                                                short* __restrict__ W2t) {
  int idx = blockIdx.x * 256 + threadIdx.x;      // 384 blocks
  if (idx < 32768) {                             // W1t [256][128]
    int f = idx >> 7, k = idx & 127;
    float v = (k < DIN_) ? W1[k * H_ + f] : 0.f;
    W1t[idx] = f2bf(v);
  } else {                                       // W2t [256][256]
    int j = idx - 32768;
    int f = j >> 8, k = j & 255;
    W2t[j] = f2bf(W2[k * H_ + f]);
  }
}

// In-register xs -> agg: acc holds xw (C/D layout: col=i16, row=q*4+e per 16-tile).
// acc2 += At @ (dinv*xw) over k=0..127 via intra-wave shuffle B-frags.
__device__ __forceinline__ void agg_from_acc(const f32x4* acc, const f32x4* dvr,
                                             char* smem, int i16, int q,
                                             f32x4* acc2) {
  unsigned P[8][2];
#pragma unroll
  for (int mt = 0; mt < 8; ++mt) {
#pragma unroll
    for (int j = 0; j < 2; ++j)
      P[mt][j] = pack2(acc[mt][2 * j] * dvr[mt][2 * j],
                       acc[mt][2 * j + 1] * dvr[mt][2 * j + 1]);
  }
  const int srcA = i16 + 32 * (q & 1);
  const int srcB = srcA + 16;
  const bool hi = q >= 2;
#pragma unroll
  for (int ks = 0; ks < 4; ++ks) {
    unsigned a0 = (unsigned)__shfl((int)P[2 * ks][0], srcA);
    unsigned b0 = (unsigned)__shfl((int)P[2 * ks + 1][0], srcA);
    unsigned a1 = (unsigned)__shfl((int)P[2 * ks][1], srcA);
    unsigned b1 = (unsigned)__shfl((int)P[2 * ks + 1][1], srcA);
    unsigned a2 = (unsigned)__shfl((int)P[2 * ks][0], srcB);
    unsigned b2 = (unsigned)__shfl((int)P[2 * ks + 1][0], srcB);
    unsigned a3 = (unsigned)__shfl((int)P[2 * ks][1], srcB);
    unsigned b3 = (unsigned)__shfl((int)P[2 * ks + 1][1], srcB);
    U8 bf;
    bf.u[0] = hi ? b0 : a0;
    bf.u[1] = hi ? b1 : a1;
    bf.u[2] = hi ? b2 : a2;
    bf.u[3] = hi ? b3 : a3;
#pragma unroll
    for (int ct = 0; ct < 8; ++ct) {
      int bb = (ks * 4 + q) ^ (i16 & 7);
      short8 atf = *(const short8*)(smem + AT_OFF + (ct * 16 + i16) * 256 + bb * 16);
      acc2[ct] = __builtin_amdgcn_mfma_f32_16x16x32_bf16(atf, bf.s, acc2[ct], 0, 0, 0);
    }
  }
}

__global__ void __launch_bounds__(512, 2) gnn_fused(
    const float* __restrict__ mM, const float* __restrict__ nf,
    const float* __restrict__ b1, const float* __restrict__ b2,
    const float* __restrict__ Wc, const float* __restrict__ bc,
    const short* __restrict__ W1t, const short* __restrict__ W2t,
    float* __restrict__ out)
{
  extern __shared__ char smem[];
  const int b    = blockIdx.x;
  const int tid  = threadIdx.x;
  const int lane = tid & 63;
  const int w    = tid >> 6;     // 0..7 : which 16-col f group
  const int i16  = lane & 15;
  const int q    = lane >> 4;

  float* dinvp = (float*)(smem + DINV_OFF);

  // ---- zero At + X (covers padding rows/cols) ----
  for (int t = tid; t < 65536 / 16; t += 512)
    ((int4v*)(smem + AT_OFF))[t] = (int4v){0, 0, 0, 0};
  __syncthreads();

  // ---- fill At (transposed, relu, +1 diag) and X (bf16), coalesced f32x4 reads ----
  {
    const float* mB = mM + (size_t)b * (R_ * R_);
    const float* xB = nf + (size_t)b * (R_ * DIN_);   // contiguous batch slice
    for (int t4 = tid; t4 < (R_ * R_) / 4; t4 += 512) {
      f32x4 v4 = ((const f32x4*)mB)[t4];
      f32x4 x4 = ((const f32x4*)xB)[t4];
#pragma unroll
      for (int e = 0; e < 4; ++e) {
        int i = t4 * 4 + e;
        int r = i / R_, c = i - r * R_;
        float v = v4[e];
        v = v > 0.f ? v : 0.f;
        if (r == c) v += 1.f;
        int ba = (r >> 3) ^ (c & 7);
        *(short*)(smem + AT_OFF + c * 256 + ba * 16 + (r & 7) * 2) = f2bf(v);
        int bx = (c >> 3) ^ (r & 7);
        *(short*)(smem + X_OFF + r * 256 + bx * 16 + (c & 7) * 2) = f2bf(x4[e]);
      }
    }
  }
  __syncthreads();

  // ---- deg/dinv: 4 threads per row ----
  {
    int row = tid >> 2, part = tid & 3;
    float s = 0.f;
#pragma unroll
    for (int j = 0; j < 4; ++j) {
      int bb = (part * 4 + j) ^ (row & 7);
      short8 v = *(const short8*)(smem + AT_OFF + row * 256 + bb * 16);
#pragma unroll
      for (int e = 0; e < 8; ++e) s += bf2f(v[e]);
    }
    s += __shfl_xor(s, 1);
    s += __shfl_xor(s, 2);
    if ((tid & 3) == 0) dinvp[row] = (row < R_) ? rsqrtf(s) : 0.f;
  }
  __syncthreads();

  f32x4 dvr[8];
#pragma unroll
  for (int mt = 0; mt < 8; ++mt) dvr[mt] = *(const f32x4*)(dinvp + mt * 16 + q * 4);

  const int fbl = w * 16 + i16;

  // ================= Layer 1 =================
#pragma unroll 1
  for (int pass = 0; pass < 2; ++pass) {
    const int f = pass * 128 + fbl;
    f32x4 acc[8];
#pragma unroll
    for (int mt = 0; mt < 8; ++mt) acc[mt] = (f32x4){0.f, 0.f, 0.f, 0.f};

#pragma unroll
    for (int ks = 0; ks < 4; ++ks) {
      short8 wf = *(const short8*)(W1t + (size_t)f * 128 + ks * 32 + q * 8);
#pragma unroll
      for (int mt = 0; mt < 8; ++mt) {
        int bb = (ks * 4 + q) ^ (i16 & 7);
        short8 af = *(const short8*)(smem + X_OFF + (mt * 16 + i16) * 256 + bb * 16);
        acc[mt] = __builtin_amdgcn_mfma_f32_16x16x32_bf16(af, wf, acc[mt], 0, 0, 0);
      }
    }

    f32x4 acc2[8];
#pragma unroll
    for (int ct = 0; ct < 8; ++ct) acc2[ct] = (f32x4){0.f, 0.f, 0.f, 0.f};
    agg_from_acc(acc, dvr, smem, i16, q, acc2);

    float bias = b1[f];
    const int fB = f >> 3, f7 = (f & 7) * 2;
#pragma unroll
    for (int ct = 0; ct < 8; ++ct) {
#pragma unroll
      for (int e = 0; e < 4; ++e) {
        int c = ct * 16 + q * 4 + e;
        float h = dvr[ct][e] * acc2[ct][e] + bias;
        h = h > 0.f ? h : 0.2f * h;
        int bb = fB ^ (c & 7);
        *(short*)(smem + H1_OFF + c * 512 + bb * 16 + f7) = f2bf(h);
      }
    }
  }
  __syncthreads();   // H1 complete

  // ================= Layer 2 =================
  float ps0 = 0.f, ps1 = 0.f;
#pragma unroll 1
  for (int pass = 0; pass < 2; ++pass) {
    const int f = pass * 128 + fbl;
    f32x4 acc[8];
#pragma unroll
    for (int mt = 0; mt < 8; ++mt) acc[mt] = (f32x4){0.f, 0.f, 0.f, 0.f};

#pragma unroll
    for (int ks = 0; ks < 8; ++ks) {
      short8 wf = *(const short8*)(W2t + (size_t)f * 256 + ks * 32 + q * 8);
#pragma unroll
      for (int mt = 0; mt < 8; ++mt) {
        int bb = (ks * 4 + q) ^ (i16 & 7);
        short8 af = *(const short8*)(smem + H1_OFF + (mt * 16 + i16) * 512 + bb * 16);
        acc[mt] = __builtin_amdgcn_mfma_f32_16x16x32_bf16(af, wf, acc[mt], 0, 0, 0);
      }
    }

    f32x4 acc2[8];
#pragma unroll
    for (int ct = 0; ct < 8; ++ct) acc2[ct] = (f32x4){0.f, 0.f, 0.f, 0.f};
    agg_from_acc(acc, dvr, smem, i16, q, acc2);

    float bias = b2[f];
#pragma unroll
    for (int ct = 0; ct < 8; ++ct) {
#pragma unroll
      for (int e = 0; e < 4; ++e) {
        int c = ct * 16 + q * 4 + e;
        if (c < R_) {
          float h = dvr[ct][e] * acc2[ct][e] + bias;
          h = h > 0.f ? h : 0.2f * h;
          size_t j = (size_t)c * H_ + f;
          ps0 += h * Wc[j];
          ps1 += h * Wc[(size_t)(H_ * R_) + j];
        }
      }
    }
  }

  // ---- classifier reduction ----
#pragma unroll
  for (int off = 32; off; off >>= 1) {
    ps0 += __shfl_xor(ps0, off, 64);
    ps1 += __shfl_xor(ps1, off, 64);
  }
  float* red = (float*)(smem + RED_OFF);
  if (lane == 0) { red[w * 2] = ps0; red[w * 2 + 1] = ps1; }
  __syncthreads();
  if (tid == 0) {
    float s0 = 0.f, s1 = 0.f;
    for (int i = 0; i < 8; ++i) { s0 += red[i * 2]; s1 += red[i * 2 + 1]; }
    out[b * 2 + 0] = s0 + bc[0];
    out[b * 2 + 1] = s1 + bc[1];
  }
}

extern "C" void kernel_launch(void* const* d_in, const int* in_sizes, int n_in,
                              void* d_out, int out_size, void* d_ws, size_t ws_size,
                              hipStream_t stream) {
  const float* mM = (const float*)d_in[0];
  const float* nf = (const float*)d_in[1];
  const float* W1 = (const float*)d_in[2];
  const float* b1 = (const float*)d_in[3];
  const float* W2 = (const float*)d_in[4];
  const float* b2 = (const float*)d_in[5];
  const float* Wc = (const float*)d_in[6];
  const float* bc = (const float*)d_in[7];
  float* out = (float*)d_out;

  short* W1t = (short*)d_ws;            // 32768 bf16
  short* W2t = W1t + 32768;             // 65536 bf16

  wt_setup<<<384, 256, 0, stream>>>(W1, W2, W1t, W2t);

  hipFuncSetAttribute((const void*)gnn_fused,
                      hipFuncAttributeMaxDynamicSharedMemorySize, LDS_SIZE);
  gnn_fused<<<512, 512, LDS_SIZE, stream>>>(mM, nf, b1, b2, Wc, bc, W1t, W2t, out);
}